// Round 2
// baseline (5566.216 us; speedup 1.0000x reference)
//
#include <hip/hip_runtime.h>

#define EPSBN 1e-5f

__device__ __forceinline__ float ftanh(float x) {
    // tanh(x) = 1 - 2/(exp(2x)+1); exact at 0, saturates correctly at +/-inf
    return 1.0f - 2.0f / (__expf(2.0f * x) + 1.0f);
}

__device__ __forceinline__ float wave_sum(float v) {
#pragma unroll
    for (int off = 32; off > 0; off >>= 1) v += __shfl_down(v, off);
    return v;
}

// z1 = cat(h_i, h_j) @ msg_w1 + msg_b1   (w row-major [8][8])
__device__ __forceinline__ void z1_of(const float4 hi, const float4 hj,
                                      const float* __restrict__ w, const float* __restrict__ b,
                                      float* z) {
#pragma unroll
    for (int j = 0; j < 8; ++j) {
        z[j] = b[j]
             + hi.x * w[0 * 8 + j] + hi.y * w[1 * 8 + j] + hi.z * w[2 * 8 + j] + hi.w * w[3 * 8 + j]
             + hj.x * w[4 * 8 + j] + hj.y * w[5 * 8 + j] + hj.z * w[6 * 8 + j] + hj.w * w[7 * 8 + j];
    }
}

__device__ __forceinline__ void mat8x8(const float* u, const float* __restrict__ w,
                                       const float* __restrict__ b, float* z) {
#pragma unroll
    for (int j = 0; j < 8; ++j) {
        float t = b[j];
#pragma unroll
        for (int k = 0; k < 8; ++k) t += u[k] * w[k * 8 + j];
        z[j] = t;
    }
}

__device__ __forceinline__ void mat8x4(const float* u, const float* __restrict__ w,
                                       const float* __restrict__ b, float* z) {
#pragma unroll
    for (int c = 0; c < 4; ++c) {
        float t = b[c];
#pragma unroll
        for (int k = 0; k < 8; ++k) t += u[k] * w[k * 4 + c];
        z[c] = t;
    }
}

// ---------------- node input projection ----------------
__global__ __launch_bounds__(256) void k_h(const float* __restrict__ pos, const float* __restrict__ vel,
                                           const float* __restrict__ w, const float* __restrict__ b,
                                           float4* __restrict__ h, int n) {
    int i = blockIdx.x * blockDim.x + threadIdx.x;
    if (i >= n) return;
    float2 p = ((const float2*)pos)[i];
    float2 v = ((const float2*)vel)[i];
    float o[4];
#pragma unroll
    for (int d = 0; d < 4; ++d)
        o[d] = b[d] + p.x * w[0 * 4 + d] + p.y * w[1 * 4 + d] + v.x * w[2 * 4 + d] + v.y * w[3 * 4 + d];
    h[i] = make_float4(o[0], o[1], o[2], o[3]);
}

// ---------------- edge pass 1: z1 stats (NO atomics per edge) ----------------
__global__ __launch_bounds__(256) void e_stats1(const int* __restrict__ idx, const float4* __restrict__ h,
                                                const float* __restrict__ w1, const float* __restrict__ b1,
                                                float* __restrict__ sums, int E_) {
    float acc[16];
#pragma unroll
    for (int i = 0; i < 16; ++i) acc[i] = 0.f;
    int stride = gridDim.x * blockDim.x;
    for (int e = blockIdx.x * blockDim.x + threadIdx.x; e < E_; e += stride) {
        int s = idx[e], d = idx[E_ + e];
        float4 hi = h[d], hj = h[s];
        float z[8];
        z1_of(hi, hj, w1, b1, z);
#pragma unroll
        for (int j = 0; j < 8; ++j) { acc[j] += z[j]; acc[8 + j] += z[j] * z[j]; }
    }
#pragma unroll
    for (int i = 0; i < 16; ++i) {
        float v = wave_sum(acc[i]);
        if ((threadIdx.x & 63) == 0) atomicAdd(&sums[i], v);
    }
}

// ---------------- finalize BN stats -> scale/shift ----------------
__global__ void k_fin(const float* __restrict__ sums, float* __restrict__ ss,
                      const float* __restrict__ g, const float* __restrict__ be,
                      int d, float inv_count) {
    int j = threadIdx.x;
    if (j >= d) return;
    float mu = sums[j] * inv_count;
    float var = sums[d + j] * inv_count - mu * mu;
    float s = g[j] * rsqrtf(var + EPSBN);
    ss[j] = s;
    ss[d + j] = be[j] - mu * s;
}

// ---------------- edge pass 2: z2 stats ----------------
__global__ __launch_bounds__(256) void e_stats2(const int* __restrict__ idx, const float4* __restrict__ h,
                                                const float* __restrict__ w1, const float* __restrict__ b1,
                                                const float* __restrict__ ss1,
                                                const float* __restrict__ w2, const float* __restrict__ b2,
                                                float* __restrict__ sums2, int E_) {
    float acc[8];
#pragma unroll
    for (int i = 0; i < 8; ++i) acc[i] = 0.f;
    int stride = gridDim.x * blockDim.x;
    for (int e = blockIdx.x * blockDim.x + threadIdx.x; e < E_; e += stride) {
        int s = idx[e], d = idx[E_ + e];
        float4 hi = h[d], hj = h[s];
        float z[8], m1[8], z2[4];
        z1_of(hi, hj, w1, b1, z);
#pragma unroll
        for (int j = 0; j < 8; ++j) m1[j] = ftanh(z[j] * ss1[j] + ss1[8 + j]);
        mat8x4(m1, w2, b2, z2);
#pragma unroll
        for (int c = 0; c < 4; ++c) { acc[c] += z2[c]; acc[4 + c] += z2[c] * z2[c]; }
    }
#pragma unroll
    for (int i = 0; i < 8; ++i) {
        float v = wave_sum(acc[i]);
        if ((threadIdx.x & 63) == 0) atomicAdd(&sums2[i], v);
    }
}

// ---------------- edge pass 3: full message + scatter (interleaved acc) ----------------
// acc layout: acc[8*d + {0:add0, 1:add1, 2:sum0, 3:sum1, 4:cnt, 5..7 pad}]
// -> all 5 atomics per edge land in ONE 32B sector of one cache line.
__global__ __launch_bounds__(256) void e_scatter(const int* __restrict__ idx, const float4* __restrict__ h,
                                                 const float* __restrict__ w1, const float* __restrict__ b1,
                                                 const float* __restrict__ ss1,
                                                 const float* __restrict__ w2, const float* __restrict__ b2,
                                                 const float* __restrict__ ss2,
                                                 float* __restrict__ acc, int E_) {
    int stride = gridDim.x * blockDim.x;
    for (int e = blockIdx.x * blockDim.x + threadIdx.x; e < E_; e += stride) {
        int s = idx[e], d = idx[E_ + e];
        float4 hi = h[d], hj = h[s];
        float* a = acc + 8 * (size_t)d;
        bool zero = (hi.x == hj.x) && (hi.y == hj.y) && (hi.z == hj.z) && (hi.w == hj.w);
        if (!zero) {
            float z[8], m1[8], z2[4], m2[4];
            z1_of(hi, hj, w1, b1, z);
#pragma unroll
            for (int j = 0; j < 8; ++j) m1[j] = ftanh(z[j] * ss1[j] + ss1[8 + j]);
            mat8x4(m1, w2, b2, z2);
#pragma unroll
            for (int c = 0; c < 4; ++c) m2[c] = ftanh(z2[c] * ss2[c] + ss2[4 + c]);
            atomicAdd(a + 0, m2[0]);
            atomicAdd(a + 1, m2[1]);
            atomicAdd(a + 2, m2[2]);
            atomicAdd(a + 3, m2[3]);
        }
        atomicAdd(a + 4, 1.0f);  // degree count includes zero-diff edges
    }
}

// ---------------- node update MLP helpers ----------------
__device__ __forceinline__ void load_u(int i, const float4* __restrict__ h,
                                       const float* __restrict__ acc, float* u) {
    float4 hv = h[i];
    const float4* a4 = (const float4*)(acc + 8 * (size_t)i);
    float4 m = a4[0];
    float c = fmaxf(a4[1].x, 1.0f);
    u[0] = hv.x; u[1] = hv.y; u[2] = hv.z; u[3] = hv.w;
    u[4] = m.x; u[5] = m.y; u[6] = m.z / c; u[7] = m.w / c;
}

// node pass 1: z3 stats
__global__ __launch_bounds__(256) void n_stats1(const float4* __restrict__ h,
                                                const float* __restrict__ acc,
                                                const float* __restrict__ w, const float* __restrict__ b,
                                                float* __restrict__ sums, int n) {
    float a[16];
#pragma unroll
    for (int i = 0; i < 16; ++i) a[i] = 0.f;
    int stride = gridDim.x * blockDim.x;
    for (int i = blockIdx.x * blockDim.x + threadIdx.x; i < n; i += stride) {
        float u[8], z[8];
        load_u(i, h, acc, u);
        mat8x8(u, w, b, z);
#pragma unroll
        for (int j = 0; j < 8; ++j) { a[j] += z[j]; a[8 + j] += z[j] * z[j]; }
    }
#pragma unroll
    for (int i = 0; i < 16; ++i) {
        float v = wave_sum(a[i]);
        if ((threadIdx.x & 63) == 0) atomicAdd(&sums[i], v);
    }
}

// node pass 2: z4 stats
__global__ __launch_bounds__(256) void n_stats2(const float4* __restrict__ h,
                                                const float* __restrict__ acc,
                                                const float* __restrict__ w1, const float* __restrict__ b1,
                                                const float* __restrict__ ss3,
                                                const float* __restrict__ w2, const float* __restrict__ b2,
                                                float* __restrict__ sums, int n) {
    float a[8];
#pragma unroll
    for (int i = 0; i < 8; ++i) a[i] = 0.f;
    int stride = gridDim.x * blockDim.x;
    for (int i = blockIdx.x * blockDim.x + threadIdx.x; i < n; i += stride) {
        float u[8], z[8], u1[8], z4[4];
        load_u(i, h, acc, u);
        mat8x8(u, w1, b1, z);
#pragma unroll
        for (int j = 0; j < 8; ++j) u1[j] = ftanh(z[j] * ss3[j] + ss3[8 + j]);
        mat8x4(u1, w2, b2, z4);
#pragma unroll
        for (int c = 0; c < 4; ++c) { a[c] += z4[c]; a[4 + c] += z4[c] * z4[c]; }
    }
#pragma unroll
    for (int i = 0; i < 8; ++i) {
        float v = wave_sum(a[i]);
        if ((threadIdx.x & 63) == 0) atomicAdd(&sums[i], v);
    }
}

// node pass 3: final output
__global__ __launch_bounds__(256) void n_final(const float4* __restrict__ h,
                                               const float* __restrict__ acc,
                                               const float* __restrict__ w1, const float* __restrict__ b1,
                                               const float* __restrict__ ss3,
                                               const float* __restrict__ w2, const float* __restrict__ b2,
                                               const float* __restrict__ ss4,
                                               const float* __restrict__ pw, const float* __restrict__ pb,
                                               float2* __restrict__ out, int n) {
    int stride = gridDim.x * blockDim.x;
    for (int i = blockIdx.x * blockDim.x + threadIdx.x; i < n; i += stride) {
        float u[8], z[8], u1[8], z4[4], u2[4];
        load_u(i, h, acc, u);
        mat8x8(u, w1, b1, z);
#pragma unroll
        for (int j = 0; j < 8; ++j) u1[j] = ftanh(z[j] * ss3[j] + ss3[8 + j]);
        mat8x4(u1, w2, b2, z4);
#pragma unroll
        for (int c = 0; c < 4; ++c) u2[c] = ftanh(z4[c] * ss4[c] + ss4[4 + c]);
        float o0 = pb[0] + u2[0] * pw[0] + u2[1] * pw[2] + u2[2] * pw[4] + u2[3] * pw[6];
        float o1 = pb[1] + u2[0] * pw[1] + u2[1] * pw[3] + u2[2] * pw[5] + u2[3] * pw[7];
        out[i] = make_float2(o0, o1);
    }
}

extern "C" void kernel_launch(void* const* d_in, const int* in_sizes, int n_in,
                              void* d_out, int out_size, void* d_ws, size_t ws_size,
                              hipStream_t stream) {
    const float* pos  = (const float*)d_in[0];
    const float* vel  = (const float*)d_in[1];
    const int*   eidx = (const int*)d_in[2];
    const float* lin_w = (const float*)d_in[3];
    const float* lin_b = (const float*)d_in[4];
    const float* mw1 = (const float*)d_in[5];
    const float* mb1 = (const float*)d_in[6];
    const float* mg1 = (const float*)d_in[7];
    const float* mbe1 = (const float*)d_in[8];
    const float* mw2 = (const float*)d_in[9];
    const float* mb2 = (const float*)d_in[10];
    const float* mg2 = (const float*)d_in[11];
    const float* mbe2 = (const float*)d_in[12];
    const float* uw1 = (const float*)d_in[13];
    const float* ub1 = (const float*)d_in[14];
    const float* ug1 = (const float*)d_in[15];
    const float* ube1 = (const float*)d_in[16];
    const float* uw2 = (const float*)d_in[17];
    const float* ub2 = (const float*)d_in[18];
    const float* ug2 = (const float*)d_in[19];
    const float* ube2 = (const float*)d_in[20];
    const float* pw = (const float*)d_in[21];
    const float* pb = (const float*)d_in[22];

    int n  = in_sizes[0] / 2;
    int E_ = in_sizes[2] / 2;

    float* ws = (float*)d_ws;
    size_t N4 = 4 * (size_t)n;
    float4* h   = (float4*)ws;                 // 4N floats
    float* acc  = ws + N4;                     // 8N floats, interleaved per-node record
    float* sums = ws + N4 + 8 * (size_t)n;     // 64 floats
    float* ss   = sums + 64;                   // 64 floats

    // zero accumulators (acc + stats sums) every launch
    hipMemsetAsync(acc, 0, (8 * (size_t)n + 64) * sizeof(float), stream);

    int nblk = (n + 255) / 256;
    const int eblk = 2048;

    k_h<<<nblk, 256, 0, stream>>>(pos, vel, lin_w, lin_b, h, n);

    e_stats1<<<eblk, 256, 0, stream>>>(eidx, h, mw1, mb1, sums, E_);
    k_fin<<<1, 64, 0, stream>>>(sums, ss, mg1, mbe1, 8, 1.0f / (float)E_);

    e_stats2<<<eblk, 256, 0, stream>>>(eidx, h, mw1, mb1, ss, mw2, mb2, sums + 16, E_);
    k_fin<<<1, 64, 0, stream>>>(sums + 16, ss + 16, mg2, mbe2, 4, 1.0f / (float)E_);

    e_scatter<<<eblk, 256, 0, stream>>>(eidx, h, mw1, mb1, ss, mw2, mb2, ss + 16, acc, E_);

    n_stats1<<<nblk, 256, 0, stream>>>(h, acc, uw1, ub1, sums + 24, n);
    k_fin<<<1, 64, 0, stream>>>(sums + 24, ss + 24, ug1, ube1, 8, 1.0f / (float)n);

    n_stats2<<<nblk, 256, 0, stream>>>(h, acc, uw1, ub1, ss + 24, uw2, ub2, sums + 40, n);
    k_fin<<<1, 64, 0, stream>>>(sums + 40, ss + 40, ug2, ube2, 4, 1.0f / (float)n);

    n_final<<<nblk, 256, 0, stream>>>(h, acc, uw1, ub1, ss + 24, uw2, ub2, ss + 40,
                                      pw, pb, (float2*)d_out, n);
}

// Round 4
// 2135.388 us; speedup vs baseline: 2.6067x; 2.6067x over previous
//
#include <hip/hip_runtime.h>

#define EPSBN 1e-5f

typedef float vf4 __attribute__((ext_vector_type(4)));

__device__ __forceinline__ float ftanh(float x) {
    return 1.0f - 2.0f / (__expf(2.0f * x) + 1.0f);
}

__device__ __forceinline__ float wave_sum(float v) {
#pragma unroll
    for (int off = 32; off > 0; off >>= 1) v += __shfl_down(v, off);
    return v;
}

// z1 = cat(h_i, h_j) @ msg_w1 + msg_b1   (w row-major [8][8])
__device__ __forceinline__ void z1_of(const float4 hi, const float4 hj,
                                      const float* __restrict__ w, const float* __restrict__ b,
                                      float* z) {
#pragma unroll
    for (int j = 0; j < 8; ++j) {
        z[j] = b[j]
             + hi.x * w[0 * 8 + j] + hi.y * w[1 * 8 + j] + hi.z * w[2 * 8 + j] + hi.w * w[3 * 8 + j]
             + hj.x * w[4 * 8 + j] + hj.y * w[5 * 8 + j] + hj.z * w[6 * 8 + j] + hj.w * w[7 * 8 + j];
    }
}

__device__ __forceinline__ void mat8x8(const float* u, const float* __restrict__ w,
                                       const float* __restrict__ b, float* z) {
#pragma unroll
    for (int j = 0; j < 8; ++j) {
        float t = b[j];
#pragma unroll
        for (int k = 0; k < 8; ++k) t += u[k] * w[k * 8 + j];
        z[j] = t;
    }
}

__device__ __forceinline__ void mat8x4(const float* u, const float* __restrict__ w,
                                       const float* __restrict__ b, float* z) {
#pragma unroll
    for (int c = 0; c < 4; ++c) {
        float t = b[c];
#pragma unroll
        for (int k = 0; k < 8; ++k) t += u[k] * w[k * 4 + c];
        z[c] = t;
    }
}

// block-level reduction of NV per-thread partials -> NV global atomics per block
template <int NV>
__device__ __forceinline__ void block_reduce_atomics(float* a, float* __restrict__ sums) {
    __shared__ float red[NV * 4];
    int wid = threadIdx.x >> 6, lane = threadIdx.x & 63;
#pragma unroll
    for (int i = 0; i < NV; ++i) {
        float v = wave_sum(a[i]);
        if (lane == 0) red[i * 4 + wid] = v;
    }
    __syncthreads();
    if (threadIdx.x < NV) {
        float v = red[threadIdx.x * 4 + 0] + red[threadIdx.x * 4 + 1]
                + red[threadIdx.x * 4 + 2] + red[threadIdx.x * 4 + 3];
        atomicAdd(&sums[threadIdx.x], v);
    }
}

// ---------------- node input projection ----------------
__global__ __launch_bounds__(256) void k_h(const float* __restrict__ pos, const float* __restrict__ vel,
                                           const float* __restrict__ w, const float* __restrict__ b,
                                           float4* __restrict__ h, int n) {
    int i = blockIdx.x * blockDim.x + threadIdx.x;
    if (i >= n) return;
    float2 p = ((const float2*)pos)[i];
    float2 v = ((const float2*)vel)[i];
    float o[4];
#pragma unroll
    for (int d = 0; d < 4; ++d)
        o[d] = b[d] + p.x * w[0 * 4 + d] + p.y * w[1 * 4 + d] + v.x * w[2 * 4 + d] + v.y * w[3 * 4 + d];
    h[i] = make_float4(o[0], o[1], o[2], o[3]);
}

// ---------------- E1: the ONLY gather pass ----------------
// gathers h_i,h_j; writes 32B record/edge (NT); z1 stats in-register; cnt atomics
__global__ __launch_bounds__(256) void e_pass1(const int* __restrict__ idx, const float4* __restrict__ h,
                                               const float* __restrict__ w1, const float* __restrict__ b1,
                                               vf4* __restrict__ rec, float* __restrict__ acc,
                                               float* __restrict__ sums, int E_) {
    float a[16];
#pragma unroll
    for (int i = 0; i < 16; ++i) a[i] = 0.f;
    int stride = gridDim.x * blockDim.x;
    for (int e = blockIdx.x * blockDim.x + threadIdx.x; e < E_; e += stride) {
        int s = __builtin_nontemporal_load(idx + e);
        int d = __builtin_nontemporal_load(idx + E_ + e);
        float4 hi = h[d], hj = h[s];
        float z[8];
        z1_of(hi, hj, w1, b1, z);
#pragma unroll
        for (int j = 0; j < 8; ++j) { a[j] += z[j]; a[8 + j] += z[j] * z[j]; }
        vf4 vi = {hi.x, hi.y, hi.z, hi.w};
        vf4 vj = {hj.x, hj.y, hj.z, hj.w};
        __builtin_nontemporal_store(vi, &rec[2 * (size_t)e]);
        __builtin_nontemporal_store(vj, &rec[2 * (size_t)e + 1]);
        atomicAdd(acc + 8 * (size_t)d + 4, 1.0f);  // degree count (all edges)
    }
    block_reduce_atomics<16>(a, sums);
}

// ---------------- finalize BN stats -> scale/shift ----------------
__global__ void k_fin(const float* __restrict__ sums, float* __restrict__ ss,
                      const float* __restrict__ g, const float* __restrict__ be,
                      int d, float inv_count) {
    int j = threadIdx.x;
    if (j >= d) return;
    float mu = sums[j] * inv_count;
    float var = sums[d + j] * inv_count - mu * mu;
    float s = g[j] * rsqrtf(var + EPSBN);
    ss[j] = s;
    ss[d + j] = be[j] - mu * s;
}

// ---------------- E2: sequential record read -> z2 stats ----------------
__global__ __launch_bounds__(256) void e_pass2(const vf4* __restrict__ rec,
                                               const float* __restrict__ w1, const float* __restrict__ b1,
                                               const float* __restrict__ ss1,
                                               const float* __restrict__ w2, const float* __restrict__ b2,
                                               float* __restrict__ sums2, int E_) {
    float a[8];
#pragma unroll
    for (int i = 0; i < 8; ++i) a[i] = 0.f;
    int stride = gridDim.x * blockDim.x;
    for (int e = blockIdx.x * blockDim.x + threadIdx.x; e < E_; e += stride) {
        vf4 vi = __builtin_nontemporal_load(&rec[2 * (size_t)e]);
        vf4 vj = __builtin_nontemporal_load(&rec[2 * (size_t)e + 1]);
        float4 hi = make_float4(vi.x, vi.y, vi.z, vi.w);
        float4 hj = make_float4(vj.x, vj.y, vj.z, vj.w);
        float z[8], m1[8], z2[4];
        z1_of(hi, hj, w1, b1, z);
#pragma unroll
        for (int j = 0; j < 8; ++j) m1[j] = ftanh(z[j] * ss1[j] + ss1[8 + j]);
        mat8x4(m1, w2, b2, z2);
#pragma unroll
        for (int c = 0; c < 4; ++c) { a[c] += z2[c]; a[4 + c] += z2[c] * z2[c]; }
    }
    block_reduce_atomics<8>(a, sums2);
}

// ---------------- E3: sequential record read -> message -> scatter ----------------
__global__ __launch_bounds__(256) void e_pass3(const vf4* __restrict__ rec, const int* __restrict__ idx,
                                               const float* __restrict__ w1, const float* __restrict__ b1,
                                               const float* __restrict__ ss1,
                                               const float* __restrict__ w2, const float* __restrict__ b2,
                                               const float* __restrict__ ss2,
                                               float* __restrict__ acc, int E_) {
    int stride = gridDim.x * blockDim.x;
    for (int e = blockIdx.x * blockDim.x + threadIdx.x; e < E_; e += stride) {
        vf4 vi = __builtin_nontemporal_load(&rec[2 * (size_t)e]);
        vf4 vj = __builtin_nontemporal_load(&rec[2 * (size_t)e + 1]);
        bool zero = (vi.x == vj.x) && (vi.y == vj.y) && (vi.z == vj.z) && (vi.w == vj.w);
        if (zero) continue;
        float4 hi = make_float4(vi.x, vi.y, vi.z, vi.w);
        float4 hj = make_float4(vj.x, vj.y, vj.z, vj.w);
        int d = __builtin_nontemporal_load(idx + E_ + e);
        float z[8], m1[8], z2[4], m2[4];
        z1_of(hi, hj, w1, b1, z);
#pragma unroll
        for (int j = 0; j < 8; ++j) m1[j] = ftanh(z[j] * ss1[j] + ss1[8 + j]);
        mat8x4(m1, w2, b2, z2);
#pragma unroll
        for (int c = 0; c < 4; ++c) m2[c] = ftanh(z2[c] * ss2[c] + ss2[4 + c]);
        float* ap = acc + 8 * (size_t)d;
        atomicAdd(ap + 0, m2[0]);
        atomicAdd(ap + 1, m2[1]);
        atomicAdd(ap + 2, m2[2]);
        atomicAdd(ap + 3, m2[3]);
    }
}

// ---------------- fallback edge kernels (round-1 style, used if ws too small) ----------------
__global__ __launch_bounds__(256) void fb_stats1(const int* __restrict__ idx, const float4* __restrict__ h,
                                                 const float* __restrict__ w1, const float* __restrict__ b1,
                                                 float* __restrict__ sums, float* __restrict__ acc, int E_) {
    float a[16];
#pragma unroll
    for (int i = 0; i < 16; ++i) a[i] = 0.f;
    int stride = gridDim.x * blockDim.x;
    for (int e = blockIdx.x * blockDim.x + threadIdx.x; e < E_; e += stride) {
        int s = idx[e], d = idx[E_ + e];
        float4 hi = h[d], hj = h[s];
        float z[8];
        z1_of(hi, hj, w1, b1, z);
#pragma unroll
        for (int j = 0; j < 8; ++j) { a[j] += z[j]; a[8 + j] += z[j] * z[j]; }
        atomicAdd(acc + 8 * (size_t)d + 4, 1.0f);
    }
    block_reduce_atomics<16>(a, sums);
}

__global__ __launch_bounds__(256) void fb_stats2(const int* __restrict__ idx, const float4* __restrict__ h,
                                                 const float* __restrict__ w1, const float* __restrict__ b1,
                                                 const float* __restrict__ ss1,
                                                 const float* __restrict__ w2, const float* __restrict__ b2,
                                                 float* __restrict__ sums2, int E_) {
    float a[8];
#pragma unroll
    for (int i = 0; i < 8; ++i) a[i] = 0.f;
    int stride = gridDim.x * blockDim.x;
    for (int e = blockIdx.x * blockDim.x + threadIdx.x; e < E_; e += stride) {
        int s = idx[e], d = idx[E_ + e];
        float4 hi = h[d], hj = h[s];
        float z[8], m1[8], z2[4];
        z1_of(hi, hj, w1, b1, z);
#pragma unroll
        for (int j = 0; j < 8; ++j) m1[j] = ftanh(z[j] * ss1[j] + ss1[8 + j]);
        mat8x4(m1, w2, b2, z2);
#pragma unroll
        for (int c = 0; c < 4; ++c) { a[c] += z2[c]; a[4 + c] += z2[c] * z2[c]; }
    }
    block_reduce_atomics<8>(a, sums2);
}

__global__ __launch_bounds__(256) void fb_scatter(const int* __restrict__ idx, const float4* __restrict__ h,
                                                  const float* __restrict__ w1, const float* __restrict__ b1,
                                                  const float* __restrict__ ss1,
                                                  const float* __restrict__ w2, const float* __restrict__ b2,
                                                  const float* __restrict__ ss2,
                                                  float* __restrict__ acc, int E_) {
    int stride = gridDim.x * blockDim.x;
    for (int e = blockIdx.x * blockDim.x + threadIdx.x; e < E_; e += stride) {
        int s = idx[e], d = idx[E_ + e];
        float4 hi = h[d], hj = h[s];
        bool zero = (hi.x == hj.x) && (hi.y == hj.y) && (hi.z == hj.z) && (hi.w == hj.w);
        if (zero) continue;
        float z[8], m1[8], z2[4], m2[4];
        z1_of(hi, hj, w1, b1, z);
#pragma unroll
        for (int j = 0; j < 8; ++j) m1[j] = ftanh(z[j] * ss1[j] + ss1[8 + j]);
        mat8x4(m1, w2, b2, z2);
#pragma unroll
        for (int c = 0; c < 4; ++c) m2[c] = ftanh(z2[c] * ss2[c] + ss2[4 + c]);
        float* ap = acc + 8 * (size_t)d;
        atomicAdd(ap + 0, m2[0]);
        atomicAdd(ap + 1, m2[1]);
        atomicAdd(ap + 2, m2[2]);
        atomicAdd(ap + 3, m2[3]);
    }
}

// ---------------- node update MLP ----------------
__device__ __forceinline__ void load_u(int i, const float4* __restrict__ h,
                                       const float* __restrict__ acc, float* u) {
    float4 hv = h[i];
    const float4* a4 = (const float4*)(acc + 8 * (size_t)i);
    float4 m = a4[0];
    float c = fmaxf(a4[1].x, 1.0f);
    u[0] = hv.x; u[1] = hv.y; u[2] = hv.z; u[3] = hv.w;
    u[4] = m.x; u[5] = m.y; u[6] = m.z / c; u[7] = m.w / c;
}

__global__ __launch_bounds__(256) void n_stats1(const float4* __restrict__ h,
                                                const float* __restrict__ acc,
                                                const float* __restrict__ w, const float* __restrict__ b,
                                                float* __restrict__ sums, int n) {
    float a[16];
#pragma unroll
    for (int i = 0; i < 16; ++i) a[i] = 0.f;
    int stride = gridDim.x * blockDim.x;
    for (int i = blockIdx.x * blockDim.x + threadIdx.x; i < n; i += stride) {
        float u[8], z[8];
        load_u(i, h, acc, u);
        mat8x8(u, w, b, z);
#pragma unroll
        for (int j = 0; j < 8; ++j) { a[j] += z[j]; a[8 + j] += z[j] * z[j]; }
    }
    block_reduce_atomics<16>(a, sums);
}

__global__ __launch_bounds__(256) void n_stats2(const float4* __restrict__ h,
                                                const float* __restrict__ acc,
                                                const float* __restrict__ w1, const float* __restrict__ b1,
                                                const float* __restrict__ ss3,
                                                const float* __restrict__ w2, const float* __restrict__ b2,
                                                float* __restrict__ sums, int n) {
    float a[8];
#pragma unroll
    for (int i = 0; i < 8; ++i) a[i] = 0.f;
    int stride = gridDim.x * blockDim.x;
    for (int i = blockIdx.x * blockDim.x + threadIdx.x; i < n; i += stride) {
        float u[8], z[8], u1[8], z4[4];
        load_u(i, h, acc, u);
        mat8x8(u, w1, b1, z);
#pragma unroll
        for (int j = 0; j < 8; ++j) u1[j] = ftanh(z[j] * ss3[j] + ss3[8 + j]);
        mat8x4(u1, w2, b2, z4);
#pragma unroll
        for (int c = 0; c < 4; ++c) { a[c] += z4[c]; a[4 + c] += z4[c] * z4[c]; }
    }
    block_reduce_atomics<8>(a, sums);
}

__global__ __launch_bounds__(256) void n_final(const float4* __restrict__ h,
                                               const float* __restrict__ acc,
                                               const float* __restrict__ w1, const float* __restrict__ b1,
                                               const float* __restrict__ ss3,
                                               const float* __restrict__ w2, const float* __restrict__ b2,
                                               const float* __restrict__ ss4,
                                               const float* __restrict__ pw, const float* __restrict__ pb,
                                               float2* __restrict__ out, int n) {
    int stride = gridDim.x * blockDim.x;
    for (int i = blockIdx.x * blockDim.x + threadIdx.x; i < n; i += stride) {
        float u[8], z[8], u1[8], z4[4], u2[4];
        load_u(i, h, acc, u);
        mat8x8(u, w1, b1, z);
#pragma unroll
        for (int j = 0; j < 8; ++j) u1[j] = ftanh(z[j] * ss3[j] + ss3[8 + j]);
        mat8x4(u1, w2, b2, z4);
#pragma unroll
        for (int c = 0; c < 4; ++c) u2[c] = ftanh(z4[c] * ss4[c] + ss4[4 + c]);
        float o0 = pb[0] + u2[0] * pw[0] + u2[1] * pw[2] + u2[2] * pw[4] + u2[3] * pw[6];
        float o1 = pb[1] + u2[0] * pw[1] + u2[1] * pw[3] + u2[2] * pw[5] + u2[3] * pw[7];
        out[i] = make_float2(o0, o1);
    }
}

extern "C" void kernel_launch(void* const* d_in, const int* in_sizes, int n_in,
                              void* d_out, int out_size, void* d_ws, size_t ws_size,
                              hipStream_t stream) {
    const float* pos  = (const float*)d_in[0];
    const float* vel  = (const float*)d_in[1];
    const int*   eidx = (const int*)d_in[2];
    const float* lin_w = (const float*)d_in[3];
    const float* lin_b = (const float*)d_in[4];
    const float* mw1 = (const float*)d_in[5];
    const float* mb1 = (const float*)d_in[6];
    const float* mg1 = (const float*)d_in[7];
    const float* mbe1 = (const float*)d_in[8];
    const float* mw2 = (const float*)d_in[9];
    const float* mb2 = (const float*)d_in[10];
    const float* mg2 = (const float*)d_in[11];
    const float* mbe2 = (const float*)d_in[12];
    const float* uw1 = (const float*)d_in[13];
    const float* ub1 = (const float*)d_in[14];
    const float* ug1 = (const float*)d_in[15];
    const float* ube1 = (const float*)d_in[16];
    const float* uw2 = (const float*)d_in[17];
    const float* ub2 = (const float*)d_in[18];
    const float* ug2 = (const float*)d_in[19];
    const float* ube2 = (const float*)d_in[20];
    const float* pw = (const float*)d_in[21];
    const float* pb = (const float*)d_in[22];

    int n  = in_sizes[0] / 2;
    int E_ = in_sizes[2] / 2;

    float* ws = (float*)d_ws;
    size_t N4 = 4 * (size_t)n;
    float4* h   = (float4*)ws;                 // 4N floats
    float* acc  = ws + N4;                     // 8N floats, per-node record {add0,add1,sum0,sum1,cnt,pad3}
    float* sums = ws + N4 + 8 * (size_t)n;     // 64 floats
    float* ss   = sums + 64;                   // 64 floats
    // per-edge record area, 16B aligned
    size_t rec_off = N4 + 8 * (size_t)n + 128;
    rec_off = (rec_off + 3) & ~(size_t)3;
    vf4* rec = (vf4*)(ws + rec_off);           // 2E vf4 = 32B/edge

    size_t need = (rec_off + 8 * (size_t)E_) * sizeof(float);
    bool big = ws_size >= need;

    hipMemsetAsync(acc, 0, (8 * (size_t)n + 64) * sizeof(float), stream);

    int nblk = (n + 255) / 256;
    const int eblk = 4096;

    k_h<<<nblk, 256, 0, stream>>>(pos, vel, lin_w, lin_b, h, n);

    if (big) {
        e_pass1<<<eblk, 256, 0, stream>>>(eidx, h, mw1, mb1, rec, acc, sums, E_);
        k_fin<<<1, 64, 0, stream>>>(sums, ss, mg1, mbe1, 8, 1.0f / (float)E_);

        e_pass2<<<eblk, 256, 0, stream>>>(rec, mw1, mb1, ss, mw2, mb2, sums + 16, E_);
        k_fin<<<1, 64, 0, stream>>>(sums + 16, ss + 16, mg2, mbe2, 4, 1.0f / (float)E_);

        e_pass3<<<eblk, 256, 0, stream>>>(rec, eidx, mw1, mb1, ss, mw2, mb2, ss + 16, acc, E_);
    } else {
        fb_stats1<<<eblk, 256, 0, stream>>>(eidx, h, mw1, mb1, sums, acc, E_);
        k_fin<<<1, 64, 0, stream>>>(sums, ss, mg1, mbe1, 8, 1.0f / (float)E_);

        fb_stats2<<<eblk, 256, 0, stream>>>(eidx, h, mw1, mb1, ss, mw2, mb2, sums + 16, E_);
        k_fin<<<1, 64, 0, stream>>>(sums + 16, ss + 16, mg2, mbe2, 4, 1.0f / (float)E_);

        fb_scatter<<<eblk, 256, 0, stream>>>(eidx, h, mw1, mb1, ss, mw2, mb2, ss + 16, acc, E_);
    }

    n_stats1<<<nblk, 256, 0, stream>>>(h, acc, uw1, ub1, sums + 24, n);
    k_fin<<<1, 64, 0, stream>>>(sums + 24, ss + 24, ug1, ube1, 8, 1.0f / (float)n);

    n_stats2<<<nblk, 256, 0, stream>>>(h, acc, uw1, ub1, ss + 24, uw2, ub2, sums + 40, n);
    k_fin<<<1, 64, 0, stream>>>(sums + 40, ss + 40, ug2, ube2, 4, 1.0f / (float)n);

    n_final<<<nblk, 256, 0, stream>>>(h, acc, uw1, ub1, ss + 24, uw2, ub2, ss + 40,
                                      pw, pb, (float2*)d_out, n);
}